// Round 1
// baseline (153.506 us; speedup 1.0000x reference)
//
#include <hip/hip_runtime.h>

// MultiKeyframeProcessor — linear keyframe interpolation.
// latents:       [K=5, B=1, C=128, H=32, W=32] f32
// strengths:     [K=5] f32
// frame_indices: [K=5] i32 (sorted, unique, < 257)
// out: conditioning_latents [1,128,257,32,32] f32 (33,685,504 el)
//      ++ conditioning_masks [1,257] f32 (257 el)

#define T_FRAMES 257
#define KK 5
#define PER_KEY 131072      // B*C*H*W = 1*128*32*32
#define HW 1024             // 32*32
#define HW4 256             // HW/4
#define LAT_OUT 33685504    // 128*257*1024

__global__ __launch_bounds__(256) void mkp_kernel(
    const float* __restrict__ lat,
    const float* __restrict__ str,
    const int* __restrict__ fi,
    float* __restrict__ out,
    int total4)
{
    const int g = blockIdx.x * blockDim.x + threadIdx.x;

    // Keyframe tables: uniform (scalar) loads, K=5 is tiny.
    int   fiv[KK];
    float sv[KK];
#pragma unroll
    for (int k = 0; k < KK; ++k) { fiv[k] = fi[k]; sv[k] = str[k]; }

    if (g < total4) {
        // flat float4 index -> (c, t, hw4); layout [C][T][HW]
        const int c   = g / (T_FRAMES * HW4);
        const int rem = g - c * (T_FRAMES * HW4);
        const int t   = rem >> 8;     // / HW4
        const int hw4 = rem & (HW4 - 1);

        // searchsorted(fi, t, right) - 1
        int j = -1;
#pragma unroll
        for (int k = 0; k < KK; ++k) j += (fiv[k] <= t) ? 1 : 0;
        const int j0 = max(j, 0);
        const int j1 = min(j + 1, KK - 1);

        const bool before   = t < fiv[0];
        const bool after    = t > fiv[KK - 1];
        const bool at_kf    = (fiv[j0] == t);
        const bool interior = !(before || after || at_kf);

        const float fj0   = (float)fiv[j0];
        const float fj1   = (float)fiv[j1];
        const float denom = fmaxf(fj1 - fj0, 1.0f);
        const float alpha = ((float)t - fj0) / denom;
        const float w1    = interior ? alpha : 0.0f;
        const float w0    = 1.0f - w1;

        const float4* l0 = (const float4*)(lat + j0 * PER_KEY + c * HW) + hw4;
        const float4* l1 = (const float4*)(lat + j1 * PER_KEY + c * HW) + hw4;
        const float4 a = *l0;
        const float4 b = *l1;
        float4 r;
        r.x = w0 * a.x + w1 * b.x;
        r.y = w0 * a.y + w1 * b.y;
        r.z = w0 * a.z + w1 * b.z;
        r.w = w0 * a.w + w1 * b.w;
        ((float4*)out)[g] = r;
    }

    // conditioning_masks tail: one thread per frame t
    if (g < T_FRAMES) {
        const int t = g;
        int j = -1;
#pragma unroll
        for (int k = 0; k < KK; ++k) j += (fiv[k] <= t) ? 1 : 0;
        const int j0 = max(j, 0);
        const int j1 = min(j + 1, KK - 1);

        const bool before   = t < fiv[0];
        const bool after    = t > fiv[KK - 1];
        const bool at_kf    = (fiv[j0] == t);
        const bool interior = !(before || after || at_kf);

        const float tf    = (float)t;
        const float fj0   = (float)fiv[j0];
        const float fj1   = (float)fiv[j1];
        const float denom = fmaxf(fj1 - fj0, 1.0f);
        const float alpha = (tf - fj0) / denom;
        const float w1    = interior ? alpha : 0.0f;
        const float w0    = 1.0f - w1;

        float m;
        if (before) {
            const float f0f = (float)fiv[0];
            m = sv[0] * fmaxf(1.0f - (f0f - tf) / fmaxf(f0f, 1.0f), 0.0f);
        } else if (after) {
            const float fLf = (float)fiv[KK - 1];
            m = sv[KK - 1] * fmaxf(1.0f - (tf - fLf) / ((float)T_FRAMES - fLf), 0.0f);
        } else {
            m = w0 * sv[j0] + w1 * sv[j1];
        }
        out[LAT_OUT + t] = m;
    }
}

extern "C" void kernel_launch(void* const* d_in, const int* in_sizes, int n_in,
                              void* d_out, int out_size, void* d_ws, size_t ws_size,
                              hipStream_t stream)
{
    const float* lat = (const float*)d_in[0];
    const float* str = (const float*)d_in[1];
    const int*   fi  = (const int*)d_in[2];
    float* out = (float*)d_out;

    const int total4 = LAT_OUT / 4;              // 8,421,376 float4 stores
    const int block  = 256;
    const int grid   = (total4 + block - 1) / block;
    mkp_kernel<<<grid, block, 0, stream>>>(lat, str, fi, out, total4);
}